// Round 2
// baseline (179.948 us; speedup 1.0000x reference)
//
#include <hip/hip_runtime.h>

// PositionDropout: out[b,s,d] = scale(b,s) * x[b,s,d]
// scale(b,s) = bernoulli(prox) / (prox + 1e-5), bernoulli drawn with JAX
// threefry2x32, key = (0,42), partitionable random_bits (bits = o0 ^ o1 with
// counter (0, row)). Verified bit-exact vs reference in round 1 (absmax 0.03
// from f32 mul assoc, within threshold).
//
// Fused single kernel: one wave (64 lanes) per row (b,s). Each wave computes
// the row's threefry + prox once (wave-uniform, ~220 VALU cyc — hidden under
// ~600 memory cyc/row), then streams the row's 192 float4s in 3 perfectly
// coalesced 1 KB wave-transactions.

static constexpr int Bn = 64, Sn = 512, Dn = 768;
static constexpr int ROWS = Bn * Sn;            // 32768 rows
static constexpr int F4_PER_ROW = Dn / 4;       // 192

__device__ __forceinline__ unsigned rotl32(unsigned x, int d) {
  return (x << d) | (x >> (32 - d));
}

// Threefry-2x32, 20 rounds, key hard-coded to (0, 42) = jax.random.key(42)
__device__ __forceinline__ void threefry2x32_0_42(unsigned x0, unsigned x1,
                                                  unsigned& o0, unsigned& o1) {
  const unsigned ks0 = 0u;
  const unsigned ks1 = 42u;
  const unsigned ks2 = 0u ^ 42u ^ 0x1BD11BDAu;
  unsigned v0 = x0 + ks0;
  unsigned v1 = x1 + ks1;
#define RG(a, b, c, d)                       \
  v0 += v1; v1 = rotl32(v1, a); v1 ^= v0;    \
  v0 += v1; v1 = rotl32(v1, b); v1 ^= v0;    \
  v0 += v1; v1 = rotl32(v1, c); v1 ^= v0;    \
  v0 += v1; v1 = rotl32(v1, d); v1 ^= v0;
  RG(13, 15, 26, 6)   v0 += ks1; v1 += ks2 + 1u;
  RG(17, 29, 16, 24)  v0 += ks2; v1 += ks0 + 2u;
  RG(13, 15, 26, 6)   v0 += ks0; v1 += ks1 + 3u;
  RG(17, 29, 16, 24)  v0 += ks1; v1 += ks2 + 4u;
  RG(13, 15, 26, 6)   v0 += ks2; v1 += ks0 + 5u;
#undef RG
  o0 = v0;
  o1 = v1;
}

// Exactly mirrors the reference's f32 op sequence so u < prox matches bitwise.
__device__ __forceinline__ float row_scale(int row,
                                           const int* __restrict__ abi,
                                           const int* __restrict__ tl,
                                           const int* __restrict__ al) {
  unsigned o0, o1;
  threefry2x32_0_42(0u, (unsigned)row, o0, o1);
  unsigned bits = o0 ^ o1;

  int b = row >> 9;          // row / Sn
  int s = row & (Sn - 1);    // row % Sn
  float jf  = (float)s;
  float b0f = (float)abi[2 * b];
  float b1f = (float)abi[2 * b + 1];
  int   tli = tl[b];
  float tlf = (float)tli;
  float ctx = (float)(tli - al[b]);   // int sub then exact cvt

  float prox;
  if (jf < b0f)       prox = 1.0f - (b0f - jf) / ctx;
  else if (jf <= b1f) prox = 1.0f / ctx;
  else                prox = 1.0f - (jf - b1f) / ctx;
  prox = (jf < tlf) ? prox : 0.0f;
  prox = fminf(fmaxf(prox, 0.0f), 1.0f);

  // JAX uniform: bitcast((bits>>9)|0x3f800000) - 1.0  in [0,1)
  float u = __uint_as_float((bits >> 9) | 0x3f800000u) - 1.0f;
  float mask = (u < prox) ? 1.0f : 0.0f;
  return mask / (prox + 1e-5f);
}

// One wave per row. Block = 256 threads = 4 waves = 4 rows.
__global__ void __launch_bounds__(256)
pos_dropout_fused(const float4* __restrict__ x,
                  const int* __restrict__ abi,
                  const int* __restrict__ tl,
                  const int* __restrict__ al,
                  float4* __restrict__ out) {
  int gtid = blockIdx.x * 256 + threadIdx.x;
  int row  = gtid >> 6;          // global wave id == row, 0..ROWS-1
  int lane = gtid & 63;

  float s = row_scale(row, abi, tl, al);   // wave-uniform

  int base = row * F4_PER_ROW + lane;      // 192 float4/row, 3 per lane
  float4 v0 = x[base];
  float4 v1 = x[base + 64];
  float4 v2 = x[base + 128];
  v0.x *= s; v0.y *= s; v0.z *= s; v0.w *= s;
  v1.x *= s; v1.y *= s; v1.z *= s; v1.w *= s;
  v2.x *= s; v2.y *= s; v2.z *= s; v2.w *= s;
  out[base]       = v0;
  out[base + 64]  = v1;
  out[base + 128] = v2;
}

extern "C" void kernel_launch(void* const* d_in, const int* in_sizes, int n_in,
                              void* d_out, int out_size, void* d_ws, size_t ws_size,
                              hipStream_t stream) {
  const float* x  = (const float*)d_in[0];
  const int* abi  = (const int*)d_in[1];   // [B,2]
  const int* tl   = (const int*)d_in[2];   // [B]
  const int* al   = (const int*)d_in[3];   // [B]
  float* out = (float*)d_out;

  // ROWS waves -> ROWS*64 threads -> ROWS/4 blocks of 256
  pos_dropout_fused<<<ROWS / 4, 256, 0, stream>>>(
      (const float4*)x, abi, tl, al, (float4*)out);
}

// Round 4
// 169.887 us; speedup vs baseline: 1.0592x; 1.0592x over previous
//
#include <hip/hip_runtime.h>

// PositionDropout: out[b,s,d] = scale(b,s) * x[b,s,d]
// scale(b,s) = bernoulli(prox) / (prox + 1e-5), bernoulli = JAX threefry2x32,
// key (0,42), partitionable random_bits (bits = o0 ^ o1, counter (0, row)).
// Bit-exact vs reference (verified rounds 1-2, absmax 0.03 = f32 mul assoc).
//
// R4 = R3 retry: nontemporal load/store, but with clang native vectors
// (__builtin_nontemporal_* rejects HIP_vector_type structs). Theory: R2's
// 60.4 us @ 1.67 TB/s write BW is L2 write-allocate (RFO) on the output
// stream adding ~100 MB hidden fetches; nt stores avoid the allocate.

static constexpr int Bn = 64, Sn = 512, Dn = 768;
static constexpr int ROWS = Bn * Sn;            // 32768 rows
static constexpr int F4_PER_ROW = Dn / 4;       // 192

typedef float vfloat4 __attribute__((ext_vector_type(4)));

__device__ __forceinline__ unsigned rotl32(unsigned x, int d) {
  return (x << d) | (x >> (32 - d));
}

// Threefry-2x32, 20 rounds, key hard-coded to (0, 42) = jax.random.key(42)
__device__ __forceinline__ void threefry2x32_0_42(unsigned x0, unsigned x1,
                                                  unsigned& o0, unsigned& o1) {
  const unsigned ks0 = 0u;
  const unsigned ks1 = 42u;
  const unsigned ks2 = 0u ^ 42u ^ 0x1BD11BDAu;
  unsigned v0 = x0 + ks0;
  unsigned v1 = x1 + ks1;
#define RG(a, b, c, d)                       \
  v0 += v1; v1 = rotl32(v1, a); v1 ^= v0;    \
  v0 += v1; v1 = rotl32(v1, b); v1 ^= v0;    \
  v0 += v1; v1 = rotl32(v1, c); v1 ^= v0;    \
  v0 += v1; v1 = rotl32(v1, d); v1 ^= v0;
  RG(13, 15, 26, 6)   v0 += ks1; v1 += ks2 + 1u;
  RG(17, 29, 16, 24)  v0 += ks2; v1 += ks0 + 2u;
  RG(13, 15, 26, 6)   v0 += ks0; v1 += ks1 + 3u;
  RG(17, 29, 16, 24)  v0 += ks1; v1 += ks2 + 4u;
  RG(13, 15, 26, 6)   v0 += ks2; v1 += ks0 + 5u;
#undef RG
  o0 = v0;
  o1 = v1;
}

// Exactly mirrors the reference's f32 op sequence so u < prox matches bitwise.
__device__ __forceinline__ float row_scale(int row,
                                           const int* __restrict__ abi,
                                           const int* __restrict__ tl,
                                           const int* __restrict__ al) {
  unsigned o0, o1;
  threefry2x32_0_42(0u, (unsigned)row, o0, o1);
  unsigned bits = o0 ^ o1;

  int b = row >> 9;          // row / Sn
  int s = row & (Sn - 1);    // row % Sn
  float jf  = (float)s;
  float b0f = (float)abi[2 * b];
  float b1f = (float)abi[2 * b + 1];
  int   tli = tl[b];
  float tlf = (float)tli;
  float ctx = (float)(tli - al[b]);   // int sub then exact cvt

  float prox;
  if (jf < b0f)       prox = 1.0f - (b0f - jf) / ctx;
  else if (jf <= b1f) prox = 1.0f / ctx;
  else                prox = 1.0f - (jf - b1f) / ctx;
  prox = (jf < tlf) ? prox : 0.0f;
  prox = fminf(fmaxf(prox, 0.0f), 1.0f);

  // JAX uniform: bitcast((bits>>9)|0x3f800000) - 1.0  in [0,1)
  float u = __uint_as_float((bits >> 9) | 0x3f800000u) - 1.0f;
  float mask = (u < prox) ? 1.0f : 0.0f;
  return mask / (prox + 1e-5f);
}

// One wave per row. Block = 256 threads = 4 waves = 4 rows.
__global__ void __launch_bounds__(256)
pos_dropout_fused(const vfloat4* __restrict__ x,
                  const int* __restrict__ abi,
                  const int* __restrict__ tl,
                  const int* __restrict__ al,
                  vfloat4* __restrict__ out) {
  int gtid = blockIdx.x * 256 + threadIdx.x;
  int row  = gtid >> 6;          // global wave id == row, 0..ROWS-1
  int lane = gtid & 63;

  int base = row * F4_PER_ROW + lane;      // 192 float4/row, 3 per lane

  // Streaming loads first (independent of the threefry chain).
  vfloat4 v0 = __builtin_nontemporal_load(&x[base]);
  vfloat4 v1 = __builtin_nontemporal_load(&x[base + 64]);
  vfloat4 v2 = __builtin_nontemporal_load(&x[base + 128]);

  float s = row_scale(row, abi, tl, al);   // wave-uniform

  v0 *= s;
  v1 *= s;
  v2 *= s;

  // nt stores: bypass L2 allocation (no read-for-ownership on the out stream)
  __builtin_nontemporal_store(v0, &out[base]);
  __builtin_nontemporal_store(v1, &out[base + 64]);
  __builtin_nontemporal_store(v2, &out[base + 128]);
}

extern "C" void kernel_launch(void* const* d_in, const int* in_sizes, int n_in,
                              void* d_out, int out_size, void* d_ws, size_t ws_size,
                              hipStream_t stream) {
  const float* x  = (const float*)d_in[0];
  const int* abi  = (const int*)d_in[1];   // [B,2]
  const int* tl   = (const int*)d_in[2];   // [B]
  const int* al   = (const int*)d_in[3];   // [B]
  float* out = (float*)d_out;

  // ROWS waves -> ROWS*64 threads -> ROWS/4 blocks of 256
  pos_dropout_fused<<<ROWS / 4, 256, 0, stream>>>(
      (const vfloat4*)x, abi, tl, al, (vfloat4*)out);
}